// Round 1
// baseline (89.625 us; speedup 1.0000x reference)
//
#include <hip/hip_runtime.h>

typedef float f32x4 __attribute__((ext_vector_type(4)));
typedef short s16x8 __attribute__((ext_vector_type(8)));

__device__ inline unsigned short bf16_rne(float v) {
    unsigned u = __float_as_uint(v);
    u += 0x7FFFu + ((u >> 16) & 1u);
    return (unsigned short)(u >> 16);
}

// Split fp32 -> bf16 hi + bf16 lo (x ~= hi + lo, residual ~2^-17 |x|)
__device__ inline void split8(const f32x4 t0, const f32x4 t1, s16x8& h, s16x8& l) {
    #pragma unroll
    for (int j = 0; j < 4; ++j) {
        {
            unsigned short hb = bf16_rne(t0[j]);
            float hf = __uint_as_float((unsigned)hb << 16);
            unsigned short lb = bf16_rne(t0[j] - hf);
            h[j] = (short)hb; l[j] = (short)lb;
        }
        {
            unsigned short hb = bf16_rne(t1[j]);
            float hf = __uint_as_float((unsigned)hb << 16);
            unsigned short lb = bf16_rne(t1[j] - hf);
            h[4 + j] = (short)hb; l[4 + j] = (short)lb;
        }
    }
}

// Prologue: squared norms of each row of x (N rows) and y (M rows) into ws.
// ws[0..N) = |x_i|^2 ; ws[N..N+M) = |y_j|^2
__global__ void rbf_norms(const float* __restrict__ x,
                          const float* __restrict__ y,
                          float* __restrict__ ws, int N, int M) {
    int i = blockIdx.x * blockDim.x + threadIdx.x;
    if (i >= N + M) return;
    const float* row = (i < N) ? (x + (size_t)i * 64) : (y + (size_t)(i - N) * 64);
    float s = 0.f;
    #pragma unroll
    for (int j = 0; j < 16; ++j) {
        f32x4 v = *(const f32x4*)(row + j * 4);
        s += v[0]*v[0] + v[1]*v[1] + v[2]*v[2] + v[3]*v[3];
    }
    ws[i] = s;
}

// Main: out[i,j] = exp(-g * (|x_i|^2 + |y_j|^2 - 2 x_i.y_j))
// 128x128 tile per 256-thread block; 4 waves in 2x2; each wave 64x64 via
// 4x4 fragments of mfma_f32_16x16x32_bf16, K=64 in two 32-steps,
// 3 split-MFMAs per step (hi*hi + hi*lo + lo*hi).
__global__ __launch_bounds__(256) void rbf_main(
        const float* __restrict__ x, const float* __restrict__ y,
        const float* __restrict__ gamma_p, const float* __restrict__ norms,
        float* __restrict__ out, int N, int M, int nbn) {
    const int bid = blockIdx.x;
    const int bm = bid / nbn;
    const int bn = bid - bm * nbn;
    const int tid = threadIdx.x;
    const int lane = tid & 63;
    const int wid = tid >> 6;
    const int wr = wid >> 1, wc = wid & 1;
    const int brow = bm * 128 + wr * 64;
    const int bcol = bn * 128 + wc * 64;
    const int l15 = lane & 15;
    const int lk  = (lane >> 4) << 3;   // k-offset within 32-wide k-step: 0,8,16,24

    f32x4 acc[4][4];
    #pragma unroll
    for (int i = 0; i < 4; ++i)
        #pragma unroll
        for (int j = 0; j < 4; ++j)
            #pragma unroll
            for (int e = 0; e < 4; ++e)
                acc[i][j][e] = 0.0f;

    s16x8 ah[4], al[4], bh[4], bl[4];

    #pragma unroll
    for (int k0 = 0; k0 < 64; k0 += 32) {
        #pragma unroll
        for (int mf = 0; mf < 4; ++mf) {
            const float* p = x + (size_t)(brow + mf * 16 + l15) * 64 + (k0 + lk);
            f32x4 t0 = *(const f32x4*)p;
            f32x4 t1 = *(const f32x4*)(p + 4);
            split8(t0, t1, ah[mf], al[mf]);
        }
        #pragma unroll
        for (int nf = 0; nf < 4; ++nf) {
            const float* p = y + (size_t)(bcol + nf * 16 + l15) * 64 + (k0 + lk);
            f32x4 t0 = *(const f32x4*)p;
            f32x4 t1 = *(const f32x4*)(p + 4);
            split8(t0, t1, bh[nf], bl[nf]);
        }
        #pragma unroll
        for (int mf = 0; mf < 4; ++mf)
            #pragma unroll
            for (int nf = 0; nf < 4; ++nf) {
                acc[mf][nf] = __builtin_amdgcn_mfma_f32_16x16x32_bf16(ah[mf], bh[nf], acc[mf][nf], 0, 0, 0);
                acc[mf][nf] = __builtin_amdgcn_mfma_f32_16x16x32_bf16(ah[mf], bl[nf], acc[mf][nf], 0, 0, 0);
                acc[mf][nf] = __builtin_amdgcn_mfma_f32_16x16x32_bf16(al[mf], bh[nf], acc[mf][nf], 0, 0, 0);
            }
    }

    const float g = *gamma_p;
    const float* x2 = norms;
    const float* y2 = norms + N;

    float yn[4];
    int   coln[4];
    #pragma unroll
    for (int nf = 0; nf < 4; ++nf) {
        coln[nf] = bcol + nf * 16 + l15;
        yn[nf] = y2[coln[nf]];
    }

    // C/D layout (HW-verified): col = lane&15, row = (lane>>4)*4 + j
    #pragma unroll
    for (int mf = 0; mf < 4; ++mf) {
        const int rbase = brow + mf * 16 + ((lane >> 4) << 2);
        #pragma unroll
        for (int j = 0; j < 4; ++j) {
            const int row = rbase + j;
            const float xn = x2[row];
            float* orow = out + (size_t)row * M;
            #pragma unroll
            for (int nf = 0; nf < 4; ++nf) {
                const float d2 = xn + yn[nf] - 2.0f * acc[mf][nf][j];
                orow[coln[nf]] = __expf(-g * d2);
            }
        }
    }
}

extern "C" void kernel_launch(void* const* d_in, const int* in_sizes, int n_in,
                              void* d_out, int out_size, void* d_ws, size_t ws_size,
                              hipStream_t stream) {
    const float* x = (const float*)d_in[0];
    const float* y = (const float*)d_in[1];
    const float* gamma_p = (const float*)d_in[2];
    float* out = (float*)d_out;
    float* ws = (float*)d_ws;

    const int D = 64;
    const int N = in_sizes[0] / D;
    const int M = in_sizes[1] / D;

    const int total = N + M;
    rbf_norms<<<(total + 255) / 256, 256, 0, stream>>>(x, y, ws, N, M);

    const int nbm = N / 128, nbn = M / 128;
    rbf_main<<<nbm * nbn, 256, 0, stream>>>(x, y, gamma_p, ws, out, N, M, nbn);
}

// Round 2
// 88.805 us; speedup vs baseline: 1.0092x; 1.0092x over previous
//
#include <hip/hip_runtime.h>

typedef float f32x4 __attribute__((ext_vector_type(4)));
typedef short s16x8 __attribute__((ext_vector_type(8)));
typedef unsigned short u16x4 __attribute__((ext_vector_type(4)));

#if __has_builtin(__builtin_amdgcn_exp2f)
#define EXP2F(x) __builtin_amdgcn_exp2f(x)
#else
#define EXP2F(x) __expf((x) * 0.6931471805599453f)
#endif

__device__ inline unsigned short bf16_rne(float v) {
    unsigned u = __float_as_uint(v);
    u += 0x7FFFu + ((u >> 16) & 1u);
    return (unsigned short)(u >> 16);
}

__device__ inline void split1(float v, unsigned short& h, unsigned short& l) {
    unsigned short hb = bf16_rne(v);
    float hf = __uint_as_float((unsigned)hb << 16);
    h = hb;
    l = bf16_rne(v - hf);
}

// Prologue: per-row prescaled norms  nrm[r] = -g*log2e*|row|^2  for x rows then y rows,
// plus (if do_split) bf16 hi/lo split arrays xh/xl/yh/yl [rows][64].
// 16 rows per 256-thread block; 16 threads per row, 4 elems per thread.
__global__ __launch_bounds__(256) void rbf_pre(
        const float* __restrict__ x, const float* __restrict__ y,
        const float* __restrict__ gamma_p,
        float* __restrict__ nrm,
        unsigned short* __restrict__ xh, unsigned short* __restrict__ xl,
        unsigned short* __restrict__ yh, unsigned short* __restrict__ yl,
        int N, int M, int do_split) {
    const int t = threadIdx.x;
    const int r = blockIdx.x * 16 + (t >> 4);
    const int c = (t & 15) << 2;
    if (r >= N + M) return;
    const int isX = r < N;
    const int rr = isX ? r : (r - N);
    const float* src = (isX ? x : y) + (size_t)rr * 64 + c;
    f32x4 v = *(const f32x4*)src;

    float s = v[0]*v[0] + v[1]*v[1] + v[2]*v[2] + v[3]*v[3];
    s += __shfl_xor(s, 1);
    s += __shfl_xor(s, 2);
    s += __shfl_xor(s, 4);
    s += __shfl_xor(s, 8);
    if ((t & 15) == 0) {
        const float g = *gamma_p;
        nrm[r] = -g * 1.4426950408889634f * s;
    }
    if (do_split) {
        u16x4 hv, lv;
        #pragma unroll
        for (int j = 0; j < 4; ++j) {
            unsigned short hb, lb;
            split1(v[j], hb, lb);
            hv[j] = hb; lv[j] = lb;
        }
        unsigned short* hd = (isX ? xh : yh) + (size_t)rr * 64 + c;
        unsigned short* ld = (isX ? xl : yl) + (size_t)rr * 64 + c;
        *(u16x4*)hd = hv;
        *(u16x4*)ld = lv;
    }
}

// Main: out[i,j] = exp2( nx[i] + ny[j] + two_s * (x_i . y_j) )
// 128x128 tile / 256-thread block, 4 waves 2x2, each wave 64x64 via 4x4
// mfma_f32_16x16x32_bf16 fragments; 3 split-MFMAs (hh, hl, lh) per k-step.
template<bool PRE>
__global__ __launch_bounds__(256) void rbf_main(
        const float* __restrict__ x, const float* __restrict__ y,
        const unsigned short* __restrict__ xh, const unsigned short* __restrict__ xl,
        const unsigned short* __restrict__ yh, const unsigned short* __restrict__ yl,
        const float* __restrict__ gamma_p, const float* __restrict__ nrm,
        float* __restrict__ out, int N, int M, int nbn) {
    const int bid = blockIdx.x;
    const int bm = bid / nbn;
    const int bn = bid - bm * nbn;
    const int tid = threadIdx.x;
    const int lane = tid & 63;
    const int wid = tid >> 6;
    const int wr = wid >> 1, wc = wid & 1;
    const int brow = bm * 128 + wr * 64;
    const int bcol = bn * 128 + wc * 64;
    const int l15 = lane & 15;
    const int lk  = (lane >> 4) << 3;   // k-offset within 32-wide k-step

    f32x4 acc[4][4];
    #pragma unroll
    for (int i = 0; i < 4; ++i)
        #pragma unroll
        for (int j = 0; j < 4; ++j)
            #pragma unroll
            for (int e = 0; e < 4; ++e)
                acc[i][j][e] = 0.0f;

    s16x8 ah[4], al[4], bh[4], bl[4];

    #pragma unroll
    for (int k0 = 0; k0 < 64; k0 += 32) {
        if (PRE) {
            #pragma unroll
            for (int mf = 0; mf < 4; ++mf) {
                const size_t off = (size_t)(brow + mf * 16 + l15) * 64 + (k0 + lk);
                ah[mf] = *(const s16x8*)(xh + off);
                al[mf] = *(const s16x8*)(xl + off);
            }
            #pragma unroll
            for (int nf = 0; nf < 4; ++nf) {
                const size_t off = (size_t)(bcol + nf * 16 + l15) * 64 + (k0 + lk);
                bh[nf] = *(const s16x8*)(yh + off);
                bl[nf] = *(const s16x8*)(yl + off);
            }
        } else {
            #pragma unroll
            for (int mf = 0; mf < 4; ++mf) {
                const float* p = x + (size_t)(brow + mf * 16 + l15) * 64 + (k0 + lk);
                f32x4 t0 = *(const f32x4*)p;
                f32x4 t1 = *(const f32x4*)(p + 4);
                #pragma unroll
                for (int j = 0; j < 4; ++j) {
                    unsigned short hb, lb;
                    split1(t0[j], hb, lb); ah[mf][j] = (short)hb; al[mf][j] = (short)lb;
                    split1(t1[j], hb, lb); ah[mf][4+j] = (short)hb; al[mf][4+j] = (short)lb;
                }
            }
            #pragma unroll
            for (int nf = 0; nf < 4; ++nf) {
                const float* p = y + (size_t)(bcol + nf * 16 + l15) * 64 + (k0 + lk);
                f32x4 t0 = *(const f32x4*)p;
                f32x4 t1 = *(const f32x4*)(p + 4);
                #pragma unroll
                for (int j = 0; j < 4; ++j) {
                    unsigned short hb, lb;
                    split1(t0[j], hb, lb); bh[nf][j] = (short)hb; bl[nf][j] = (short)lb;
                    split1(t1[j], hb, lb); bh[nf][4+j] = (short)hb; bl[nf][4+j] = (short)lb;
                }
            }
        }
        #pragma unroll
        for (int mf = 0; mf < 4; ++mf)
            #pragma unroll
            for (int nf = 0; nf < 4; ++nf) {
                acc[mf][nf] = __builtin_amdgcn_mfma_f32_16x16x32_bf16(ah[mf], bh[nf], acc[mf][nf], 0, 0, 0);
                acc[mf][nf] = __builtin_amdgcn_mfma_f32_16x16x32_bf16(ah[mf], bl[nf], acc[mf][nf], 0, 0, 0);
                acc[mf][nf] = __builtin_amdgcn_mfma_f32_16x16x32_bf16(al[mf], bh[nf], acc[mf][nf], 0, 0, 0);
            }
    }

    const float g = *gamma_p;
    const float two_s = 2.0f * g * 1.4426950408889634f;
    const float* nx = nrm;
    const float* ny = nrm + N;

    float yn[4];
    int   coln[4];
    #pragma unroll
    for (int nf = 0; nf < 4; ++nf) {
        coln[nf] = bcol + nf * 16 + l15;
        yn[nf] = ny[coln[nf]];
    }

    // C/D layout: col = lane&15, row = (lane>>4)*4 + j
    #pragma unroll
    for (int mf = 0; mf < 4; ++mf) {
        const int rbase = brow + mf * 16 + ((lane >> 4) << 2);
        #pragma unroll
        for (int j = 0; j < 4; ++j) {
            const int row = rbase + j;
            const float xn = nx[row];
            float* orow = out + (size_t)row * M;
            #pragma unroll
            for (int nf = 0; nf < 4; ++nf) {
                const float d = fmaf(two_s, acc[mf][nf][j], xn + yn[nf]);
                orow[coln[nf]] = EXP2F(d);
            }
        }
    }
}

extern "C" void kernel_launch(void* const* d_in, const int* in_sizes, int n_in,
                              void* d_out, int out_size, void* d_ws, size_t ws_size,
                              hipStream_t stream) {
    const float* x = (const float*)d_in[0];
    const float* y = (const float*)d_in[1];
    const float* gamma_p = (const float*)d_in[2];
    float* out = (float*)d_out;

    const int D = 64;
    const int N = in_sizes[0] / D;
    const int M = in_sizes[1] / D;

    // ws layout: [nrm: (N+M) f32][xh: N*64 u16][xl][yh: M*64 u16][yl]
    char* wsb = (char*)d_ws;
    float* nrm = (float*)wsb;
    size_t off = (size_t)(N + M) * 4;
    unsigned short* xh = (unsigned short*)(wsb + off); off += (size_t)N * 64 * 2;
    unsigned short* xl = (unsigned short*)(wsb + off); off += (size_t)N * 64 * 2;
    unsigned short* yh = (unsigned short*)(wsb + off); off += (size_t)M * 64 * 2;
    unsigned short* yl = (unsigned short*)(wsb + off); off += (size_t)M * 64 * 2;
    const bool pre = (ws_size >= off);

    const int rows = N + M;
    rbf_pre<<<(rows + 15) / 16, 256, 0, stream>>>(x, y, gamma_p, nrm, xh, xl, yh, yl,
                                                  N, M, pre ? 1 : 0);

    const int nbm = N / 128, nbn = M / 128;
    if (pre)
        rbf_main<true><<<nbm * nbn, 256, 0, stream>>>(x, y, xh, xl, yh, yl, gamma_p,
                                                      nrm, out, N, M, nbn);
    else
        rbf_main<false><<<nbm * nbn, 256, 0, stream>>>(x, y, xh, xl, yh, yl, gamma_p,
                                                       nrm, out, N, M, nbn);
}

// Round 3
// 81.786 us; speedup vs baseline: 1.0958x; 1.0858x over previous
//
#include <hip/hip_runtime.h>

typedef float f32x4 __attribute__((ext_vector_type(4)));
typedef short s16x8 __attribute__((ext_vector_type(8)));
typedef unsigned short u16x4 __attribute__((ext_vector_type(4)));

#if __has_builtin(__builtin_amdgcn_exp2f)
#define EXP2F(x) __builtin_amdgcn_exp2f(x)
#else
#define EXP2F(x) __expf((x) * 0.6931471805599453f)
#endif

__device__ inline unsigned short bf16_rne(float v) {
    unsigned u = __float_as_uint(v);
    u += 0x7FFFu + ((u >> 16) & 1u);
    return (unsigned short)(u >> 16);
}

__device__ inline void split1(float v, unsigned short& h, unsigned short& l) {
    unsigned short hb = bf16_rne(v);
    float hf = __uint_as_float((unsigned)hb << 16);
    h = hb;
    l = bf16_rne(v - hf);
}

// Prologue: nrm[r] = -g*log2e*|row|^2 for x rows then y rows, plus bf16 hi/lo
// split arrays xh/xl/yh/yl. 16 rows per 256-thread block.
__global__ __launch_bounds__(256) void rbf_pre(
        const float* __restrict__ x, const float* __restrict__ y,
        const float* __restrict__ gamma_p,
        float* __restrict__ nrm,
        unsigned short* __restrict__ xh, unsigned short* __restrict__ xl,
        unsigned short* __restrict__ yh, unsigned short* __restrict__ yl,
        int N, int M, int do_split) {
    const int t = threadIdx.x;
    const int r = blockIdx.x * 16 + (t >> 4);
    const int c = (t & 15) << 2;
    if (r >= N + M) return;
    const int isX = r < N;
    const int rr = isX ? r : (r - N);
    const float* src = (isX ? x : y) + (size_t)rr * 64 + c;
    f32x4 v = *(const f32x4*)src;

    float s = v[0]*v[0] + v[1]*v[1] + v[2]*v[2] + v[3]*v[3];
    s += __shfl_xor(s, 1);
    s += __shfl_xor(s, 2);
    s += __shfl_xor(s, 4);
    s += __shfl_xor(s, 8);
    if ((t & 15) == 0) {
        const float g = *gamma_p;
        nrm[r] = -g * 1.4426950408889634f * s;
    }
    if (do_split) {
        u16x4 hv, lv;
        #pragma unroll
        for (int j = 0; j < 4; ++j) {
            unsigned short hb, lb;
            split1(v[j], hb, lb);
            hv[j] = hb; lv[j] = lb;
        }
        unsigned short* hd = (isX ? xh : yh) + (size_t)rr * 64 + c;
        unsigned short* ld = (isX ? xl : yl) + (size_t)rr * 64 + c;
        *(u16x4*)hd = hv;
        *(u16x4*)ld = lv;
    }
}

// Main: out[i,j] = exp2( nx[i] + ny[j] + two_s * (x_i . y_j) )
// 128x128 tile / 256-thread block, 4 waves 2x2, each wave 64x64 via 4x4
// mfma_f32_16x16x32_bf16 fragments; 3 split-MFMAs (hh, hl, lh) per k-step.
// Epilogue: per-wave LDS transpose bounce so every global store is
// dwordx4/lane = 4 rows x 256B contiguous (full L2 lines, no RFO).
#define LROW 68   // LDS row stride in dwords: bank = (4*(r+c)+e)%32, uniform 2-way
template<bool PRE>
__global__ __launch_bounds__(256) void rbf_main(
        const float* __restrict__ x, const float* __restrict__ y,
        const unsigned short* __restrict__ xh, const unsigned short* __restrict__ xl,
        const unsigned short* __restrict__ yh, const unsigned short* __restrict__ yl,
        const float* __restrict__ gamma_p, const float* __restrict__ nrm,
        float* __restrict__ out, int N, int M, int nbn) {
    __shared__ float lds[4][16 * LROW];

    const int bid = blockIdx.x;
    const int bm = bid / nbn;
    const int bn = bid - bm * nbn;
    const int tid = threadIdx.x;
    const int lane = tid & 63;
    const int wid = tid >> 6;
    const int wr = wid >> 1, wc = wid & 1;
    const int brow = bm * 128 + wr * 64;
    const int bcol = bn * 128 + wc * 64;
    const int l15 = lane & 15;
    const int lg  = lane >> 4;          // row group 0..3
    const int lk  = lg << 3;            // k-offset within 32-wide k-step

    f32x4 acc[4][4];
    #pragma unroll
    for (int i = 0; i < 4; ++i)
        #pragma unroll
        for (int j = 0; j < 4; ++j)
            #pragma unroll
            for (int e = 0; e < 4; ++e)
                acc[i][j][e] = 0.0f;

    s16x8 ah[4], al[4], bh[4], bl[4];

    #pragma unroll
    for (int k0 = 0; k0 < 64; k0 += 32) {
        if (PRE) {
            #pragma unroll
            for (int mf = 0; mf < 4; ++mf) {
                const size_t off = (size_t)(brow + mf * 16 + l15) * 64 + (k0 + lk);
                ah[mf] = *(const s16x8*)(xh + off);
                al[mf] = *(const s16x8*)(xl + off);
            }
            #pragma unroll
            for (int nf = 0; nf < 4; ++nf) {
                const size_t off = (size_t)(bcol + nf * 16 + l15) * 64 + (k0 + lk);
                bh[nf] = *(const s16x8*)(yh + off);
                bl[nf] = *(const s16x8*)(yl + off);
            }
        } else {
            #pragma unroll
            for (int mf = 0; mf < 4; ++mf) {
                const float* p = x + (size_t)(brow + mf * 16 + l15) * 64 + (k0 + lk);
                f32x4 t0 = *(const f32x4*)p;
                f32x4 t1 = *(const f32x4*)(p + 4);
                #pragma unroll
                for (int j = 0; j < 4; ++j) {
                    unsigned short hb, lb;
                    split1(t0[j], hb, lb); ah[mf][j] = (short)hb; al[mf][j] = (short)lb;
                    split1(t1[j], hb, lb); ah[mf][4+j] = (short)hb; al[mf][4+j] = (short)lb;
                }
            }
            #pragma unroll
            for (int nf = 0; nf < 4; ++nf) {
                const float* p = y + (size_t)(bcol + nf * 16 + l15) * 64 + (k0 + lk);
                f32x4 t0 = *(const f32x4*)p;
                f32x4 t1 = *(const f32x4*)(p + 4);
                #pragma unroll
                for (int j = 0; j < 4; ++j) {
                    unsigned short hb, lb;
                    split1(t0[j], hb, lb); bh[nf][j] = (short)hb; bl[nf][j] = (short)lb;
                    split1(t1[j], hb, lb); bh[nf][4+j] = (short)hb; bl[nf][4+j] = (short)lb;
                }
            }
        }
        #pragma unroll
        for (int mf = 0; mf < 4; ++mf)
            #pragma unroll
            for (int nf = 0; nf < 4; ++nf) {
                acc[mf][nf] = __builtin_amdgcn_mfma_f32_16x16x32_bf16(ah[mf], bh[nf], acc[mf][nf], 0, 0, 0);
                acc[mf][nf] = __builtin_amdgcn_mfma_f32_16x16x32_bf16(ah[mf], bl[nf], acc[mf][nf], 0, 0, 0);
                acc[mf][nf] = __builtin_amdgcn_mfma_f32_16x16x32_bf16(al[mf], bh[nf], acc[mf][nf], 0, 0, 0);
            }
    }

    const float g = *gamma_p;
    const float two_s = 2.0f * g * 1.4426950408889634f;
    const float* nx = nrm;
    const float* ny = nrm + N;

    float yn[4];
    #pragma unroll
    for (int nf = 0; nf < 4; ++nf)
        yn[nf] = ny[bcol + nf * 16 + l15];

    float* wl = lds[wid];

    // Per mf-slice (16 rows x 64 cols): exp -> LDS (col-major quads) ->
    // read row-major -> full-line dwordx4 stores.
    #pragma unroll
    for (int mf = 0; mf < 4; ++mf) {
        // C/D layout: col = lane&15 (within 16), row = lg*4 + j
        float xn[4];
        #pragma unroll
        for (int j = 0; j < 4; ++j)
            xn[j] = nx[brow + mf * 16 + lg * 4 + j];

        #pragma unroll
        for (int nf = 0; nf < 4; ++nf) {
            const int c = nf * 16 + l15;
            #pragma unroll
            for (int j = 0; j < 4; ++j) {
                const float d = fmaf(two_s, acc[mf][nf][j], xn[j] + yn[nf]);
                wl[(lg * 4 + j) * LROW + c] = EXP2F(d);
            }
        }
        // same-wave exchange: lgkmcnt ordering only, no barrier needed
        #pragma unroll
        for (int t = 0; t < 4; ++t) {
            const int r = t * 4 + lg;
            f32x4 v = *(const f32x4*)&wl[r * LROW + l15 * 4];
            float* dst = out + (size_t)(brow + mf * 16 + r) * M + bcol + l15 * 4;
            *(f32x4*)dst = v;
        }
    }
}

extern "C" void kernel_launch(void* const* d_in, const int* in_sizes, int n_in,
                              void* d_out, int out_size, void* d_ws, size_t ws_size,
                              hipStream_t stream) {
    const float* x = (const float*)d_in[0];
    const float* y = (const float*)d_in[1];
    const float* gamma_p = (const float*)d_in[2];
    float* out = (float*)d_out;

    const int D = 64;
    const int N = in_sizes[0] / D;
    const int M = in_sizes[1] / D;

    // ws layout: [nrm: (N+M) f32][xh: N*64 u16][xl][yh: M*64 u16][yl]
    char* wsb = (char*)d_ws;
    float* nrm = (float*)wsb;
    size_t off = (size_t)(N + M) * 4;
    unsigned short* xh = (unsigned short*)(wsb + off); off += (size_t)N * 64 * 2;
    unsigned short* xl = (unsigned short*)(wsb + off); off += (size_t)N * 64 * 2;
    unsigned short* yh = (unsigned short*)(wsb + off); off += (size_t)M * 64 * 2;
    unsigned short* yl = (unsigned short*)(wsb + off); off += (size_t)M * 64 * 2;
    const bool pre = (ws_size >= off);

    const int rows = N + M;
    rbf_pre<<<(rows + 15) / 16, 256, 0, stream>>>(x, y, gamma_p, nrm, xh, xl, yh, yl,
                                                  N, M, pre ? 1 : 0);

    const int nbm = N / 128, nbn = M / 128;
    if (pre)
        rbf_main<true><<<nbm * nbn, 256, 0, stream>>>(x, y, xh, xl, yh, yl, gamma_p,
                                                      nrm, out, N, M, nbn);
    else
        rbf_main<false><<<nbm * nbn, 256, 0, stream>>>(x, y, xh, xl, yh, yl, gamma_p,
                                                       nrm, out, N, M, nbn);
}

// Round 4
// 59.965 us; speedup vs baseline: 1.4946x; 1.3639x over previous
//
#include <hip/hip_runtime.h>

typedef float f32x4 __attribute__((ext_vector_type(4)));
typedef short s16x8 __attribute__((ext_vector_type(8)));
typedef unsigned short u16x4 __attribute__((ext_vector_type(4)));

#if __has_builtin(__builtin_amdgcn_exp2f)
#define EXP2F(x) __builtin_amdgcn_exp2f(x)
#else
#define EXP2F(x) __expf((x) * 0.6931471805599453f)
#endif

__device__ inline unsigned short bf16_rne(float v) {
    unsigned u = __float_as_uint(v);
    u += 0x7FFFu + ((u >> 16) & 1u);
    return (unsigned short)(u >> 16);
}

__device__ inline void split1(float v, unsigned short& h, unsigned short& l) {
    unsigned short hb = bf16_rne(v);
    float hf = __uint_as_float((unsigned)hb << 16);
    h = hb;
    l = bf16_rne(v - hf);
}

// Prologue: nrm[r] = -g*log2e*|row|^2 for x rows then y rows, plus bf16 hi/lo
// split arrays xh/xl/yh/yl. 16 rows per 256-thread block.
__global__ __launch_bounds__(256) void rbf_pre(
        const float* __restrict__ x, const float* __restrict__ y,
        const float* __restrict__ gamma_p,
        float* __restrict__ nrm,
        unsigned short* __restrict__ xh, unsigned short* __restrict__ xl,
        unsigned short* __restrict__ yh, unsigned short* __restrict__ yl,
        int N, int M, int do_split) {
    const int t = threadIdx.x;
    const int r = blockIdx.x * 16 + (t >> 4);
    const int c = (t & 15) << 2;
    if (r >= N + M) return;
    const int isX = r < N;
    const int rr = isX ? r : (r - N);
    const float* src = (isX ? x : y) + (size_t)rr * 64 + c;
    f32x4 v = *(const f32x4*)src;

    float s = v[0]*v[0] + v[1]*v[1] + v[2]*v[2] + v[3]*v[3];
    s += __shfl_xor(s, 1);
    s += __shfl_xor(s, 2);
    s += __shfl_xor(s, 4);
    s += __shfl_xor(s, 8);
    if ((t & 15) == 0) {
        const float g = *gamma_p;
        nrm[r] = -g * 1.4426950408889634f * s;
    }
    if (do_split) {
        u16x4 hv, lv;
        #pragma unroll
        for (int j = 0; j < 4; ++j) {
            unsigned short hb, lb;
            split1(v[j], hb, lb);
            hv[j] = hb; lv[j] = lb;
        }
        unsigned short* hd = (isX ? xh : yh) + (size_t)rr * 64 + c;
        unsigned short* ld = (isX ? xl : yl) + (size_t)rr * 64 + c;
        *(u16x4*)hd = hv;
        *(u16x4*)ld = lv;
    }
}

// Main: out[i,j] = exp2( nx[i] + ny[j] + two_s * (x_i . y_j) )
// 128x128 tile / 256-thread block, 4 waves 2x2.
// PRE path: panels LDS-staged once (XOR-swizzled), shared by all 4 waves.
// Epilogue: per-wave LDS transpose bounce (overlaid on dead staging buffer)
// -> every global store is dwordx4/lane = 4 rows x 256B full lines.
#define LROW 68
template<bool PRE>
__global__ __launch_bounds__(256, 2) void rbf_main(
        const float* __restrict__ x, const float* __restrict__ y,
        const unsigned short* __restrict__ xh, const unsigned short* __restrict__ xl,
        const unsigned short* __restrict__ yh, const unsigned short* __restrict__ yl,
        const float* __restrict__ gamma_p, const float* __restrict__ nrm,
        float* __restrict__ out, int N, int M, int nbm, int nbn) {
    __shared__ char smem[65536];   // staging: Ah@0 Al@16K Bh@32K Bl@48K; epilogue overlay

    // XCD-chunked bijective swizzle (HW round-robins blockIdx -> XCD):
    // XCD k gets logical blocks [k*chunk, (k+1)*chunk), bn-major within chunk.
    int bm, bn;
    const int nwg = nbm * nbn;
    if ((nwg & 7) == 0 && (nbm & 7) == 0) {
        const int xcd = blockIdx.x & 7;
        const int lo  = blockIdx.x >> 3;          // 0..nwg/8-1
        const int bmPerX = nbm >> 3;
        bn = lo / bmPerX;
        bm = xcd * bmPerX + (lo - bn * bmPerX);
    } else {
        bm = blockIdx.x / nbn;
        bn = blockIdx.x - bm * nbn;
    }

    const int tid = threadIdx.x;
    const int lane = tid & 63;
    const int wid = tid >> 6;
    const int wr = wid >> 1, wc = wid & 1;
    const int brow = bm * 128 + wr * 64;
    const int bcol = bn * 128 + wc * 64;
    const int l15 = lane & 15;
    const int lg  = lane >> 4;          // 0..3
    const int lk  = lg << 3;            // k-offset (shorts) within 32-wide k-step

    f32x4 acc[4][4];
    #pragma unroll
    for (int i = 0; i < 4; ++i)
        #pragma unroll
        for (int j = 0; j < 4; ++j)
            #pragma unroll
            for (int e = 0; e < 4; ++e)
                acc[i][j][e] = 0.0f;

    s16x8 ah[4], al[4], bh[4], bl[4];

    if (PRE) {
        // --- stage 4 x 16KB panels into LDS, XOR-swizzled ---
        // unit u (16B) : arr = u>>10 (Ah,Al,Bh,Bl), v=u&1023, row=v>>3, kc=v&7
        // lds byte = arr*16384 + row*128 + ((kc ^ (row&7))<<4)
        const unsigned short* src0 = xh + (size_t)bm * 128 * 64;
        const unsigned short* src1 = xl + (size_t)bm * 128 * 64;
        const unsigned short* src2 = yh + (size_t)bn * 128 * 64;
        const unsigned short* src3 = yl + (size_t)bn * 128 * 64;
        #pragma unroll
        for (int it = 0; it < 16; ++it) {
            const int u = it * 256 + tid;
            const int arr = it >> 2;             // compile-time
            const int v = u & 1023;
            const int row = v >> 3, kc = v & 7;
            const unsigned short* s =
                (arr == 0) ? src0 : (arr == 1) ? src1 : (arr == 2) ? src2 : src3;
            s16x8 d = *(const s16x8*)(s + (size_t)row * 64 + kc * 8);
            const int dst = (arr << 14) + row * 128 + ((kc ^ (row & 7)) << 4);
            *(s16x8*)(smem + dst) = d;
        }
        __syncthreads();

        #pragma unroll
        for (int k0 = 0; k0 < 64; k0 += 32) {
            const int kc = (k0 >> 3) + lg;
            #pragma unroll
            for (int mf = 0; mf < 4; ++mf) {
                const int arow = wr * 64 + mf * 16 + l15;
                const int off = arow * 128 + ((kc ^ (arow & 7)) << 4);
                ah[mf] = *(const s16x8*)(smem + off);
                al[mf] = *(const s16x8*)(smem + 16384 + off);
            }
            #pragma unroll
            for (int nf = 0; nf < 4; ++nf) {
                const int brw = wc * 64 + nf * 16 + l15;
                const int off = brw * 128 + ((kc ^ (brw & 7)) << 4);
                bh[nf] = *(const s16x8*)(smem + 32768 + off);
                bl[nf] = *(const s16x8*)(smem + 49152 + off);
            }
            #pragma unroll
            for (int mf = 0; mf < 4; ++mf)
                #pragma unroll
                for (int nf = 0; nf < 4; ++nf) {
                    acc[mf][nf] = __builtin_amdgcn_mfma_f32_16x16x32_bf16(ah[mf], bh[nf], acc[mf][nf], 0, 0, 0);
                    acc[mf][nf] = __builtin_amdgcn_mfma_f32_16x16x32_bf16(ah[mf], bl[nf], acc[mf][nf], 0, 0, 0);
                    acc[mf][nf] = __builtin_amdgcn_mfma_f32_16x16x32_bf16(al[mf], bh[nf], acc[mf][nf], 0, 0, 0);
                }
        }
        __syncthreads();   // staging buffer dead; safe to overlay epilogue bounce
    } else {
        #pragma unroll
        for (int k0 = 0; k0 < 64; k0 += 32) {
            #pragma unroll
            for (int mf = 0; mf < 4; ++mf) {
                const float* p = x + (size_t)(brow + mf * 16 + l15) * 64 + (k0 + lk);
                f32x4 t0 = *(const f32x4*)p;
                f32x4 t1 = *(const f32x4*)(p + 4);
                #pragma unroll
                for (int j = 0; j < 4; ++j) {
                    unsigned short hb, lb;
                    split1(t0[j], hb, lb); ah[mf][j] = (short)hb; al[mf][j] = (short)lb;
                    split1(t1[j], hb, lb); ah[mf][4+j] = (short)hb; al[mf][4+j] = (short)lb;
                }
            }
            #pragma unroll
            for (int nf = 0; nf < 4; ++nf) {
                const float* p = y + (size_t)(bcol + nf * 16 + l15) * 64 + (k0 + lk);
                f32x4 t0 = *(const f32x4*)p;
                f32x4 t1 = *(const f32x4*)(p + 4);
                #pragma unroll
                for (int j = 0; j < 4; ++j) {
                    unsigned short hb, lb;
                    split1(t0[j], hb, lb); bh[nf][j] = (short)hb; bl[nf][j] = (short)lb;
                    split1(t1[j], hb, lb); bh[nf][4+j] = (short)hb; bl[nf][4+j] = (short)lb;
                }
            }
            #pragma unroll
            for (int mf = 0; mf < 4; ++mf)
                #pragma unroll
                for (int nf = 0; nf < 4; ++nf) {
                    acc[mf][nf] = __builtin_amdgcn_mfma_f32_16x16x32_bf16(ah[mf], bh[nf], acc[mf][nf], 0, 0, 0);
                    acc[mf][nf] = __builtin_amdgcn_mfma_f32_16x16x32_bf16(ah[mf], bl[nf], acc[mf][nf], 0, 0, 0);
                    acc[mf][nf] = __builtin_amdgcn_mfma_f32_16x16x32_bf16(al[mf], bh[nf], acc[mf][nf], 0, 0, 0);
                }
        }
    }

    const float g = *gamma_p;
    const float two_s = 2.0f * g * 1.4426950408889634f;
    const float* nx = nrm;
    const float* ny = nrm + N;

    float yn[4];
    #pragma unroll
    for (int nf = 0; nf < 4; ++nf)
        yn[nf] = ny[bcol + nf * 16 + l15];

    float* wl = (float*)smem + wid * 16 * LROW;   // per-wave 4.25KB, overlay

    #pragma unroll
    for (int mf = 0; mf < 4; ++mf) {
        // C/D layout: col = lane&15 (within 16), row = lg*4 + j
        float xn[4];
        #pragma unroll
        for (int j = 0; j < 4; ++j)
            xn[j] = nx[brow + mf * 16 + lg * 4 + j];

        #pragma unroll
        for (int nf = 0; nf < 4; ++nf) {
            const int c = nf * 16 + l15;
            #pragma unroll
            for (int j = 0; j < 4; ++j) {
                const float d = fmaf(two_s, acc[mf][nf][j], xn[j] + yn[nf]);
                wl[(lg * 4 + j) * LROW + c] = EXP2F(d);
            }
        }
        // same-wave exchange: lgkmcnt ordering only, no barrier needed
        #pragma unroll
        for (int t = 0; t < 4; ++t) {
            const int r = t * 4 + lg;
            f32x4 v = *(const f32x4*)&wl[r * LROW + l15 * 4];
            float* dst = out + (size_t)(brow + mf * 16 + r) * M + bcol + l15 * 4;
            *(f32x4*)dst = v;
        }
    }
}

extern "C" void kernel_launch(void* const* d_in, const int* in_sizes, int n_in,
                              void* d_out, int out_size, void* d_ws, size_t ws_size,
                              hipStream_t stream) {
    const float* x = (const float*)d_in[0];
    const float* y = (const float*)d_in[1];
    const float* gamma_p = (const float*)d_in[2];
    float* out = (float*)d_out;

    const int D = 64;
    const int N = in_sizes[0] / D;
    const int M = in_sizes[1] / D;

    // ws layout: [nrm: (N+M) f32][xh: N*64 u16][xl][yh: M*64 u16][yl]
    char* wsb = (char*)d_ws;
    float* nrm = (float*)wsb;
    size_t off = (size_t)(N + M) * 4;
    unsigned short* xh = (unsigned short*)(wsb + off); off += (size_t)N * 64 * 2;
    unsigned short* xl = (unsigned short*)(wsb + off); off += (size_t)N * 64 * 2;
    unsigned short* yh = (unsigned short*)(wsb + off); off += (size_t)M * 64 * 2;
    unsigned short* yl = (unsigned short*)(wsb + off); off += (size_t)M * 64 * 2;
    const bool pre = (ws_size >= off);

    const int rows = N + M;
    rbf_pre<<<(rows + 15) / 16, 256, 0, stream>>>(x, y, gamma_p, nrm, xh, xl, yh, yl,
                                                  N, M, pre ? 1 : 0);

    const int nbm = N / 128, nbn = M / 128;
    if (pre)
        rbf_main<true><<<nbm * nbn, 256, 0, stream>>>(x, y, xh, xl, yh, yl, gamma_p,
                                                      nrm, out, N, M, nbm, nbn);
    else
        rbf_main<false><<<nbm * nbn, 256, 0, stream>>>(x, y, xh, xl, yh, yl, gamma_p,
                                                       nrm, out, N, M, nbm, nbn);
}